// Round 1
// 918.085 us; speedup vs baseline: 1.1811x; 1.1811x over previous
//
#include <hip/hip_runtime.h>
#include <hip/hip_bf16.h>
#include <stdint.h>

typedef __attribute__((ext_vector_type(8))) short short8;
typedef __attribute__((ext_vector_type(4))) float f32x4;

__device__ __forceinline__ f32x4 mfma16(short8 a, short8 b, f32x4 c) {
  return __builtin_amdgcn_mfma_f32_16x16x32_bf16(a, b, c, 0, 0, 0);
}

__device__ __forceinline__ ushort f2bf(float f) {
  __hip_bfloat16 h = __float2bfloat16(f);
  return __builtin_bit_cast(ushort, h);
}

// load 8 consecutive f32 and convert to a bf16 fragment
__device__ __forceinline__ short8 cvt8(const float* p) {
  float4 a = *(const float4*)p;
  float4 b = *(const float4*)(p + 4);
  short8 r;
  r[0] = (short)f2bf(a.x); r[1] = (short)f2bf(a.y);
  r[2] = (short)f2bf(a.z); r[3] = (short)f2bf(a.w);
  r[4] = (short)f2bf(b.x); r[5] = (short)f2bf(b.y);
  r[6] = (short)f2bf(b.z); r[7] = (short)f2bf(b.w);
  return r;
}

struct ProjArgs {
  const void* x;        // activations: f32 (xdyn=1) or bf16 (xdyn=0)
  const float* w;       // weights f32 [N,K]
  const float* b;       // bias f32
  void* out;            // bf16 ws (mode 0/1) or f32 d_out (mode 2)
  float scale; int mode; int xdyn;
};
struct ProjArgs3 { ProjArgs p[3]; };

// LDS-staged GEMM: out[row,col] = (sum_k x[row,k]*w[col,k] + b[col])*scale
// M=8192, N=512, K=512. Block tile 128x64, 4 waves (each 32 rows x 64 cols),
// BK=32. Global loads are coalesced (128B-per-row segments), staged once to
// LDS, consumed by all 4 waves. Loads for tile k are issued before the
// barrier so they overlap the previous tile's MFMAs.
__global__ __launch_bounds__(256) void proj_kernel(ProjArgs3 pa3) {
  ProjArgs pa = pa3.p[blockIdx.z];
  const int xf = pa.xdyn;
  const int tid = threadIdx.x;
  const int wave = tid >> 6, lane = tid & 63;
  const int qd = lane >> 4, n = lane & 15;
  const int rowbase = blockIdx.x * 128;
  const int colbase = blockIdx.y * 64;

  // As [128][32] bf16 (8KB) | Bs [64][32] bf16 (4KB); tbuf (mode 1) reuses
  // the same 20KB after a barrier.
  __shared__ __attribute__((aligned(16))) ushort smem[10240];
  ushort* As = smem;
  ushort* Bs = smem + 4096;

  const int srow = tid >> 2;   // 0..63
  const int schk = tid & 3;    // 8-elem k-chunk

  const f32x4 fzero = {0.f, 0.f, 0.f, 0.f};
  f32x4 acc[2][4];
#pragma unroll
  for (int r = 0; r < 2; r++)
#pragma unroll
    for (int j = 0; j < 4; j++) acc[r][j] = fzero;

  for (int k0 = 0; k0 < 512; k0 += 32) {
    short8 av0, av1, bv;
    if (xf) {
      av0 = cvt8((const float*)pa.x + (size_t)(rowbase + srow) * 512 + k0 + schk * 8);
      av1 = cvt8((const float*)pa.x + (size_t)(rowbase + 64 + srow) * 512 + k0 + schk * 8);
    } else {
      av0 = *(const short8*)((const ushort*)pa.x + (size_t)(rowbase + srow) * 512 + k0 + schk * 8);
      av1 = *(const short8*)((const ushort*)pa.x + (size_t)(rowbase + 64 + srow) * 512 + k0 + schk * 8);
    }
    bv = cvt8(pa.w + (size_t)(colbase + srow) * 512 + k0 + schk * 8);

    __syncthreads();   // previous tile's reads done
    *(short8*)&As[(srow) * 32 + schk * 8] = av0;
    *(short8*)&As[(64 + srow) * 32 + schk * 8] = av1;
    *(short8*)&Bs[(srow) * 32 + schk * 8] = bv;
    __syncthreads();   // tile visible

    short8 a0 = *(const short8*)&As[(wave * 32 + n) * 32 + qd * 8];
    short8 a1 = *(const short8*)&As[(wave * 32 + 16 + n) * 32 + qd * 8];
#pragma unroll
    for (int j = 0; j < 4; j++) {
      short8 bf = *(const short8*)&Bs[(j * 16 + n) * 32 + qd * 8];
      acc[0][j] = mfma16(a0, bf, acc[0][j]);
      acc[1][j] = mfma16(a1, bf, acc[1][j]);
    }
  }

  const int wrow = rowbase + wave * 32;

  if (pa.mode == 1) {
    // transpose epilogue: [col][row] staging in LDS, coalesced rows of vpT.
    __syncthreads();   // all waves done reading As/Bs before reuse as tbuf
    ushort* tb = smem + wave * 2560;  // [64][40]
#pragma unroll
    for (int r = 0; r < 2; r++)
#pragma unroll
      for (int j = 0; j < 4; j++)
#pragma unroll
        for (int i = 0; i < 4; i++) {
          int ol = j * 16 + n;
          int ll = r * 16 + qd * 4 + i;
          float vv = (acc[r][j][i] + pa.b[colbase + ol]) * pa.scale;
          tb[ol * 40 + ll] = f2bf(vv);
        }
    // wave-private read-back; lgkmcnt orders writes->reads
    int o = colbase + lane;
    int h2 = o >> 6, dd = o & 63;
    int bb2 = wrow >> 11, l0 = wrow & 2047;
    size_t base = ((size_t)((bb2 * 8 + h2) * 64 + dd)) * 2048 + l0;
    ushort* ob = (ushort*)pa.out;
#pragma unroll
    for (int c = 0; c < 4; c++) {
      uint4 vdata = *(const uint4*)(tb + lane * 40 + c * 8);
      *(uint4*)(ob + base + c * 8) = vdata;
    }
  } else {
#pragma unroll
    for (int r = 0; r < 2; r++)
#pragma unroll
      for (int j = 0; j < 4; j++)
#pragma unroll
        for (int i = 0; i < 4; i++) {
          int col = colbase + j * 16 + n;
          int row = wrow + r * 16 + qd * 4 + i;
          float vv = (acc[r][j][i] + pa.b[col]) * pa.scale;
          if (pa.mode == 0) {
            int bb2 = row >> 11, l = row & 2047, h2 = col >> 6, dd = col & 63;
            ((ushort*)pa.out)[((size_t)((bb2 * 8 + h2) * 2048 + l)) * 64 + dd] = f2bf(vv);
          } else {
            ((float*)pa.out)[(size_t)row * 512 + col] = vv;
          }
        }
  }
}

// Attention. Block = 256 threads = 4 waves; wave (w2,kh) handles q-rows
// [qt*32 + w2*16, +16) over k-half kh*1024..+1024. Grid (64, 8, 4) = 2048
// blocks -> 2x the wave count of the previous version (was grid-capped).
//
// Swapped-operand QK^T: mfma(kf, qf) -> lane (qd,n) holds
// S[k = kk+qd*4+i][q = q0+n], so each lane owns 4 CONSECUTIVE k:
//  - pass 1: scalar per-lane lsum (row q0+n), 2 shuffles + LDS pair-merge
//  - pass 2: one float4 nontemporal attn store + one packed uint2 LDS write
// pbuf is wave-private: NO barriers in the k-loop (lgkmcnt orders ds ops).
__global__ __launch_bounds__(256, 6) void attn_kernel(
    const ushort* __restrict__ qp, const ushort* __restrict__ kp,
    const ushort* __restrict__ vpT, const int* __restrict__ mask,
    float* __restrict__ attn, ushort* __restrict__ ao) {
  const int bb = blockIdx.z, h = blockIdx.y, qt = blockIdx.x;
  const int wave = threadIdx.x >> 6, lane = threadIdx.x & 63;
  const int qd = lane >> 4, n = lane & 15;
  const int w2 = wave >> 1;   // q sub-tile
  const int kh = wave & 1;    // k half

  __shared__ __attribute__((aligned(16))) float maskb[2048];  // reused as obuf
  __shared__ float lsbuf[64];
  __shared__ __attribute__((aligned(16))) ushort pbuf[4][16 * 40];

  {
    int i = threadIdx.x * 8;
    const int* mp = mask + bb * 2048 + i;
    int4 m0 = *(const int4*)mp;
    int4 m1 = *(const int4*)(mp + 4);
    float4 f0 = make_float4(-1e9f * m0.x, -1e9f * m0.y, -1e9f * m0.z, -1e9f * m0.w);
    float4 f1 = make_float4(-1e9f * m1.x, -1e9f * m1.y, -1e9f * m1.z, -1e9f * m1.w);
    *(float4*)&maskb[i] = f0;
    *(float4*)&maskb[i + 4] = f1;
  }
  __syncthreads();

  const size_t bh = (size_t)(bb * 8 + h);
  const ushort* qph = qp + bh * (2048 * 64);
  const ushort* kph = kp + bh * (2048 * 64);
  const ushort* vph = vpT + bh * (64 * 2048);

  const int q0 = qt * 32 + w2 * 16;
  const int kbase = kh * 1024;

  short8 qf0 = *(const short8*)(qph + (size_t)(q0 + n) * 64 + qd * 8);
  short8 qf1 = *(const short8*)(qph + (size_t)(q0 + n) * 64 + 32 + qd * 8);

  const ushort* kptr = kph + (size_t)(kbase + n) * 64 + qd * 8;
  const float* mptr = maskb + kbase + qd * 4;
  const f32x4 fzero = {0.f, 0.f, 0.f, 0.f};

  // ---- pass 1: denominators (no max subtraction: |scores| ~ 2, safe)
  float lsum = 0.f;
  for (int k0 = 0; k0 < 1024; k0 += 32) {
#pragma unroll
    for (int t = 0; t < 2; t++) {
      int kk = k0 + t * 16;
      short8 kf0 = *(const short8*)(kptr + (size_t)kk * 64);
      short8 kf1 = *(const short8*)(kptr + (size_t)kk * 64 + 32);
      f32x4 s = mfma16(kf0, qf0, fzero);
      s = mfma16(kf1, qf1, s);
      f32x4 mv = *(const f32x4*)(mptr + kk);
      float e0 = __expf(s[0] + mv[0]);
      float e1 = __expf(s[1] + mv[1]);
      float e2 = __expf(s[2] + mv[2]);
      float e3 = __expf(s[3] + mv[3]);
      lsum += (e0 + e1) + (e2 + e3);
    }
  }
  lsum += __shfl_xor(lsum, 16, 64);
  lsum += __shfl_xor(lsum, 32, 64);
  if (lane < 16) lsbuf[wave * 16 + lane] = lsum;
  __syncthreads();
  float tot = lsbuf[w2 * 32 + n] + lsbuf[w2 * 32 + 16 + n];
  float inv = 1.0f / fmaxf(tot, 1e-30f);

  // ---- pass 2: normalized attn writes (float4, nontemporal) + PV
  f32x4 oacc[4];
#pragma unroll
  for (int j = 0; j < 4; j++) oacc[j] = fzero;

  ushort* pb = pbuf[wave];
  float* arow = attn + (bh * 2048 + (size_t)(q0 + n)) * 2048 + kbase + qd * 4;
  const ushort* vptr = vph + (size_t)n * 2048 + kbase + qd * 8;

  for (int k0 = 0; k0 < 1024; k0 += 32) {
#pragma unroll
    for (int t = 0; t < 2; t++) {
      int kk = k0 + t * 16;
      short8 kf0 = *(const short8*)(kptr + (size_t)kk * 64);
      short8 kf1 = *(const short8*)(kptr + (size_t)kk * 64 + 32);
      f32x4 s = mfma16(kf0, qf0, fzero);
      s = mfma16(kf1, qf1, s);
      f32x4 mv = *(const f32x4*)(mptr + kk);
      f32x4 p;
      p[0] = __expf(s[0] + mv[0]) * inv;
      p[1] = __expf(s[1] + mv[1]) * inv;
      p[2] = __expf(s[2] + mv[2]) * inv;
      p[3] = __expf(s[3] + mv[3]) * inv;
      __builtin_nontemporal_store(p, (f32x4*)(arow + kk));
      uint2 pk2;
      pk2.x = (uint)f2bf(p[0]) | ((uint)f2bf(p[1]) << 16);
      pk2.y = (uint)f2bf(p[2]) | ((uint)f2bf(p[3]) << 16);
      *(uint2*)(pb + n * 40 + t * 16 + qd * 4) = pk2;  // P[q=n][k] bf16
    }
    // wave-private LDS: compiler's lgkmcnt orders writes -> this read
    short8 af = *(const short8*)(pb + n * 40 + qd * 8);  // A[m=n][k=qd*8+j]
#pragma unroll
    for (int j = 0; j < 4; j++) {
      short8 vf = *(const short8*)(vptr + (size_t)j * 16 * 2048 + k0);
      oacc[j] = mfma16(af, vf, oacc[j]);
    }
  }

  // ---- merge k-halves (obuf reuses maskb; everyone is past maskb reads)
  __syncthreads();
  float* obuf = maskb;
  if (kh == 1) {
#pragma unroll
    for (int j = 0; j < 4; j++)
      *(f32x4*)&obuf[((size_t)(w2 * 64 + lane)) * 16 + j * 4] = oacc[j];
  }
  __syncthreads();
  if (kh == 0) {
#pragma unroll
    for (int j = 0; j < 4; j++) {
      f32x4 o2 = *(const f32x4*)&obuf[((size_t)(w2 * 64 + lane)) * 16 + j * 4];
#pragma unroll
      for (int i = 0; i < 4; i++) oacc[j][i] += o2[i];
    }
    // epilogue: concat-head layout [B*L, 512], bf16 ws
#pragma unroll
    for (int j = 0; j < 4; j++)
#pragma unroll
      for (int i = 0; i < 4; i++) {
        int rowg = q0 + qd * 4 + i;
        int col = h * 64 + j * 16 + n;
        ao[(size_t)(bb * 2048 + rowg) * 512 + col] = f2bf(oacc[j][i]);
      }
  }
}

extern "C" void kernel_launch(void* const* d_in, const int* in_sizes, int n_in,
                              void* d_out, int out_size, void* d_ws, size_t ws_size,
                              hipStream_t stream) {
  (void)in_sizes; (void)n_in; (void)out_size; (void)ws_size;
  const void* q = d_in[0];
  const void* k = d_in[1];
  const void* v = d_in[2];
  const int* mask = (const int*)d_in[3];

  float* out = (float*)d_out;
  float* attn = out + (size_t)4 * 2048 * 512;

  ushort* qp = (ushort*)d_ws;
  ushort* kp = qp + 4194304;
  ushort* vpT = kp + 4194304;
  ushort* ao = vpT + 4194304;

  ProjArgs3 pa;
  pa.p[0] = { q, (const float*)d_in[4], (const float*)d_in[5], qp,  0.125f, 0, 1 };
  pa.p[1] = { k, (const float*)d_in[6], (const float*)d_in[7], kp,  1.0f,   0, 1 };
  pa.p[2] = { v, (const float*)d_in[8], (const float*)d_in[9], vpT, 1.0f,   1, 1 };
  proj_kernel<<<dim3(64, 8, 3), 256, 0, stream>>>(pa);

  attn_kernel<<<dim3(64, 8, 4), 256, 0, stream>>>(qp, kp, vpT, mask, attn, ao);

  ProjArgs3 po;
  po.p[0] = { ao, (const float*)d_in[10], (const float*)d_in[11], out, 1.0f, 2, 0 };
  po.p[1] = po.p[0]; po.p[2] = po.p[0];
  proj_kernel<<<dim3(64, 8, 1), 256, 0, stream>>>(po);
}

// Round 2
// 748.284 us; speedup vs baseline: 1.4492x; 1.2269x over previous
//
#include <hip/hip_runtime.h>
#include <hip/hip_bf16.h>
#include <stdint.h>

typedef __attribute__((ext_vector_type(8))) short short8;
typedef __attribute__((ext_vector_type(4))) float f32x4;

__device__ __forceinline__ f32x4 mfma16(short8 a, short8 b, f32x4 c) {
  return __builtin_amdgcn_mfma_f32_16x16x32_bf16(a, b, c, 0, 0, 0);
}

__device__ __forceinline__ ushort f2bf(float f) {
  __hip_bfloat16 h = __float2bfloat16(f);
  return __builtin_bit_cast(ushort, h);
}

// load 8 consecutive f32 and convert to a bf16 fragment
__device__ __forceinline__ short8 cvt8(const float* p) {
  float4 a = *(const float4*)p;
  float4 b = *(const float4*)(p + 4);
  short8 r;
  r[0] = (short)f2bf(a.x); r[1] = (short)f2bf(a.y);
  r[2] = (short)f2bf(a.z); r[3] = (short)f2bf(a.w);
  r[4] = (short)f2bf(b.x); r[5] = (short)f2bf(b.y);
  r[6] = (short)f2bf(b.z); r[7] = (short)f2bf(b.w);
  return r;
}

// async global->LDS, 16B per lane. LDS dest = wave-uniform base + lane*16.
typedef const __attribute__((address_space(1))) void* gvp;
typedef __attribute__((address_space(3))) void* lvp;
__device__ __forceinline__ void gl_lds16(const void* g, void* l) {
  __builtin_amdgcn_global_load_lds((gvp)g, (lvp)l, 16, 0, 0);
}

// ---------------- pre-convert: f32 -> bf16 ----------------
struct CvtArgs { const float* src; ushort* dst; int n4; };
struct CvtArgs6 { CvtArgs a[6]; };

__global__ __launch_bounds__(256) void convert_kernel(CvtArgs6 ca) {
  CvtArgs c = ca.a[blockIdx.y];
  for (int i = blockIdx.x * 256 + threadIdx.x; i < c.n4; i += gridDim.x * 256) {
    float4 f = ((const float4*)c.src)[i];
    uint2 o;
    o.x = (uint)f2bf(f.x) | ((uint)f2bf(f.y) << 16);
    o.y = (uint)f2bf(f.z) | ((uint)f2bf(f.w) << 16);
    *(uint2*)(c.dst + (size_t)i * 4) = o;
  }
}

// ---------------- projections ----------------
struct ProjArgs {
  const ushort* x;      // bf16 activations [8192,512]
  const void* w;        // weights [512,512]: bf16 (wf=0) or f32 (wf=1)
  const float* b;       // bias f32
  void* out;            // bf16 ws (mode 0/1) or f32 d_out (mode 2)
  float scale; int mode; int wf;
};
struct ProjArgs3 { ProjArgs p[3]; };

// out[row,col] = (sum_k x[row,k]*w[col,k] + b[col]) * scale
// M=8192,N=512,K=512. Tile 128x64, 4 waves, BK=32. A (and B when bf16) staged
// via global_load_lds (no VGPR transit, no cvt). LDS [row][32] bf16: frag read
// window = (row*4+qd)%8 -> uniform 8-way = b128 minimum, no swizzle needed.
__global__ __launch_bounds__(256) void proj_kernel(ProjArgs3 pa3) {
  ProjArgs pa = pa3.p[blockIdx.z];
  const int tid = threadIdx.x;
  const int wave = tid >> 6, lane = tid & 63;
  const int qd = lane >> 4, n = lane & 15;
  const int rowbase = blockIdx.x * 128;
  const int colbase = blockIdx.y * 64;

  __shared__ __attribute__((aligned(16))) ushort smem[10240];  // 20KB
  ushort* As = smem;          // [128][32]
  ushort* Bs = smem + 4096;   // [64][32]

  const int brow = tid >> 2, bchk = tid & 3;
  const int ldsw = (tid & ~63) * 8;  // wave-uniform chunk base (ushorts)

  const f32x4 fzero = {0.f, 0.f, 0.f, 0.f};
  f32x4 acc[2][4];
#pragma unroll
  for (int r = 0; r < 2; r++)
#pragma unroll
    for (int j = 0; j < 4; j++) acc[r][j] = fzero;

  for (int k0 = 0; k0 < 512; k0 += 32) {
    // A tile: 8KB in 2 async rounds (prev readers done: end-of-iter barrier)
    gl_lds16(pa.x + (size_t)(rowbase + brow) * 512 + k0 + bchk * 8, As + ldsw);
    gl_lds16(pa.x + (size_t)(rowbase + 64 + brow) * 512 + k0 + bchk * 8,
             As + 2048 + ldsw);
    if (pa.wf) {
      short8 bv = cvt8((const float*)pa.w + (size_t)(colbase + brow) * 512 + k0 + bchk * 8);
      *(short8*)&Bs[(size_t)tid * 8] = bv;
    } else {
      gl_lds16((const ushort*)pa.w + (size_t)(colbase + brow) * 512 + k0 + bchk * 8,
               Bs + ldsw);
    }
    __syncthreads();  // drains vmcnt (async LDS writes) + lgkm

    short8 a0 = *(const short8*)&As[(wave * 32 + n) * 32 + qd * 8];
    short8 a1 = *(const short8*)&As[(wave * 32 + 16 + n) * 32 + qd * 8];
#pragma unroll
    for (int j = 0; j < 4; j++) {
      short8 bf = *(const short8*)&Bs[(j * 16 + n) * 32 + qd * 8];
      acc[0][j] = mfma16(a0, bf, acc[0][j]);
      acc[1][j] = mfma16(a1, bf, acc[1][j]);
    }
    __syncthreads();  // reads done before next iter's writes
  }

  const int wrow = rowbase + wave * 32;

  if (pa.mode == 1) {
    // transpose epilogue: [col][row] stage in LDS, coalesced rows of vpT
    ushort* tb = smem + wave * 2560;  // [64][40]
#pragma unroll
    for (int r = 0; r < 2; r++)
#pragma unroll
      for (int j = 0; j < 4; j++)
#pragma unroll
        for (int i = 0; i < 4; i++) {
          int ol = j * 16 + n;
          int ll = r * 16 + qd * 4 + i;
          float vv = (acc[r][j][i] + pa.b[colbase + ol]) * pa.scale;
          tb[ol * 40 + ll] = f2bf(vv);
        }
    // wave-private read-back; lgkmcnt orders writes->reads
    int o = colbase + lane;
    int h2 = o >> 6, dd = o & 63;
    int bb2 = wrow >> 11, l0 = wrow & 2047;
    size_t base = ((size_t)((bb2 * 8 + h2) * 64 + dd)) * 2048 + l0;
    ushort* ob = (ushort*)pa.out;
#pragma unroll
    for (int c = 0; c < 4; c++) {
      uint4 vdata = *(const uint4*)(tb + lane * 40 + c * 8);
      *(uint4*)(ob + base + c * 8) = vdata;
    }
  } else {
#pragma unroll
    for (int r = 0; r < 2; r++)
#pragma unroll
      for (int j = 0; j < 4; j++)
#pragma unroll
        for (int i = 0; i < 4; i++) {
          int col = colbase + j * 16 + n;
          int row = wrow + r * 16 + qd * 4 + i;
          float vv = (acc[r][j][i] + pa.b[col]) * pa.scale;
          if (pa.mode == 0) {
            int bb2 = row >> 11, l = row & 2047, h2 = col >> 6, dd = col & 63;
            ((ushort*)pa.out)[((size_t)((bb2 * 8 + h2) * 2048 + l)) * 64 + dd] = f2bf(vv);
          } else {
            ((float*)pa.out)[(size_t)row * 512 + col] = vv;
          }
        }
  }
}

// ---------------- attention ----------------
// Block = 4 waves = 64 q rows (wave w: q0 = qt*64 + w*16), FULL k range.
// K tile (4KB) + V tile (4KB) staged once per k-step via global_load_lds,
// shared by all 4 waves -> ~8x less per-CU L2 traffic than per-wave streams.
// K is XOR-swizzled at the SOURCE (linear LDS dest, rule: both-sides-or-
// neither): LDS chunk l holds global chunk (l&~7)|((l&7)^((l>>3)&7)); the
// frag read then lands uniform 8-way (b128 minimum). V linear is already
// uniform. Double-buffered, ONE barrier per k-step.
// Swapped-operand QK^T: lane (qd,n) holds S[k=kk+qd*4+i][q=q0+n].
__global__ __launch_bounds__(256, 4) void attn_kernel(
    const ushort* __restrict__ qp, const ushort* __restrict__ kp,
    const ushort* __restrict__ vpT, const int* __restrict__ mask,
    float* __restrict__ attn, ushort* __restrict__ ao) {
  const int bb = blockIdx.z, h = blockIdx.y, qt = blockIdx.x;
  const int wave = threadIdx.x >> 6, lane = threadIdx.x & 63;
  const int qd = lane >> 4, n = lane & 15;
  const int tid = threadIdx.x;

  __shared__ __attribute__((aligned(16))) float maskb[2048];     // 8KB
  __shared__ __attribute__((aligned(16))) ushort Kb[2][2048];    // 2x4KB
  __shared__ __attribute__((aligned(16))) ushort Vb[2][2048];    // 2x4KB
  __shared__ __attribute__((aligned(16))) ushort pbuf[4][16 * 40];

  {
    int i = tid * 8;
    const int* mp = mask + bb * 2048 + i;
    int4 m0 = *(const int4*)mp;
    int4 m1 = *(const int4*)(mp + 4);
    float4 f0 = make_float4(-1e9f * m0.x, -1e9f * m0.y, -1e9f * m0.z, -1e9f * m0.w);
    float4 f1 = make_float4(-1e9f * m1.x, -1e9f * m1.y, -1e9f * m1.z, -1e9f * m1.w);
    *(float4*)&maskb[i] = f0;
    *(float4*)&maskb[i + 4] = f1;
  }

  const size_t bh = (size_t)(bb * 8 + h);
  const ushort* qph = qp + bh * (2048 * 64);
  const ushort* kph = kp + bh * (2048 * 64);
  const ushort* vph = vpT + bh * (64 * 2048);

  const int q0 = qt * 64 + wave * 16;
  short8 qf0 = *(const short8*)(qph + (size_t)(q0 + n) * 64 + qd * 8);
  short8 qf1 = *(const short8*)(qph + (size_t)(q0 + n) * 64 + 32 + qd * 8);

  // K stage: thread t copies LDS chunk t <- global chunk g (swizzled)
  const int kg = (tid & ~7) | ((tid & 7) ^ ((tid >> 3) & 7));
  const int ldsw = (tid & ~63) * 8;  // wave-uniform chunk base (ushorts)
  // V stage: thread t -> row t>>2 (stride 2048), 16B chunk t&3
  const size_t vrow = (size_t)(tid >> 2) * 2048 + (tid & 3) * 8;

  // K frag read byte offsets (swizzled): row = t*16+n, chunk c=h*4+qd:
  // addr = row*128 + ((c ^ (row&7))<<4); h=1 flips bit 6.
  const int r7 = n & 7;
  const int ka = n * 128 + ((qd ^ r7) << 4);
  // V frag read: [d=j*16+n][16B chunk qd] -> (j*16+n)*64 + qd*16 bytes
  const int va = n * 64 + qd * 16;

  const f32x4 fzero = {0.f, 0.f, 0.f, 0.f};

  // ---- pass 1: denominators (no max subtraction: |scores| ~ 2, safe)
  float lsum = 0.f;
  {
    const ushort* kt0 = kph;  // k0 = 0
#pragma unroll 1
    for (int i4 = 0; i4 < 1; i4++) {}  // (no-op, keeps structure flat)
    // prologue stage
    gl_lds16(kph + (size_t)kg * 8, (ushort*)Kb[0] + ldsw);
    (void)kt0;
  }
  __syncthreads();
  int buf = 0;
  for (int k0 = 0; k0 < 2048; k0 += 32) {
    if (k0 + 32 < 2048)
      gl_lds16(kph + (size_t)(k0 + 32) * 64 + (size_t)kg * 8,
               (ushort*)Kb[buf ^ 1] + ldsw);
    const char* KB = (const char*)Kb[buf];
#pragma unroll
    for (int t = 0; t < 2; t++) {
      int kao = ka + t * 2048;
      short8 kf0 = *(const short8*)(KB + kao);
      short8 kf1 = *(const short8*)(KB + (kao ^ 64));
      f32x4 s = mfma16(kf0, qf0, fzero);
      s = mfma16(kf1, qf1, s);
      f32x4 mv = *(const f32x4*)&maskb[k0 + t * 16 + qd * 4];
      float e0 = __expf(s[0] + mv[0]);
      float e1 = __expf(s[1] + mv[1]);
      float e2 = __expf(s[2] + mv[2]);
      float e3 = __expf(s[3] + mv[3]);
      lsum += (e0 + e1) + (e2 + e3);
    }
    __syncthreads();
    buf ^= 1;
  }
  lsum += __shfl_xor(lsum, 16, 64);
  lsum += __shfl_xor(lsum, 32, 64);
  float inv = 1.0f / fmaxf(lsum, 1e-30f);

  // ---- pass 2: normalized attn writes (float4, nontemporal) + PV
  f32x4 oacc[4];
#pragma unroll
  for (int j = 0; j < 4; j++) oacc[j] = fzero;

  ushort* pb = pbuf[wave];
  float* arow = attn + (bh * 2048 + (size_t)(q0 + n)) * 2048 + qd * 4;

  gl_lds16(kph + (size_t)kg * 8, (ushort*)Kb[0] + ldsw);
  gl_lds16(vph + vrow, (ushort*)Vb[0] + ldsw);
  __syncthreads();
  buf = 0;
  for (int k0 = 0; k0 < 2048; k0 += 32) {
    if (k0 + 32 < 2048) {
      gl_lds16(kph + (size_t)(k0 + 32) * 64 + (size_t)kg * 8,
               (ushort*)Kb[buf ^ 1] + ldsw);
      gl_lds16(vph + (k0 + 32) + vrow, (ushort*)Vb[buf ^ 1] + ldsw);
    }
    const char* KB = (const char*)Kb[buf];
    const char* VB = (const char*)Vb[buf];
#pragma unroll
    for (int t = 0; t < 2; t++) {
      int kao = ka + t * 2048;
      short8 kf0 = *(const short8*)(KB + kao);
      short8 kf1 = *(const short8*)(KB + (kao ^ 64));
      f32x4 s = mfma16(kf0, qf0, fzero);
      s = mfma16(kf1, qf1, s);
      f32x4 mv = *(const f32x4*)&maskb[k0 + t * 16 + qd * 4];
      f32x4 p;
      p[0] = __expf(s[0] + mv[0]) * inv;
      p[1] = __expf(s[1] + mv[1]) * inv;
      p[2] = __expf(s[2] + mv[2]) * inv;
      p[3] = __expf(s[3] + mv[3]) * inv;
      __builtin_nontemporal_store(p, (f32x4*)(arow + k0 + t * 16));
      uint2 pk2;
      pk2.x = (uint)f2bf(p[0]) | ((uint)f2bf(p[1]) << 16);
      pk2.y = (uint)f2bf(p[2]) | ((uint)f2bf(p[3]) << 16);
      *(uint2*)(pb + n * 40 + t * 16 + qd * 4) = pk2;  // P[q=n][k] bf16
    }
    // wave-private LDS: lgkmcnt orders writes -> this read
    short8 af = *(const short8*)(pb + n * 40 + qd * 8);  // A[m=n][k=qd*8+j]
#pragma unroll
    for (int j = 0; j < 4; j++) {
      short8 vf = *(const short8*)(VB + va + j * 1024);
      oacc[j] = mfma16(af, vf, oacc[j]);
    }
    __syncthreads();
    buf ^= 1;
  }

  // epilogue: concat-head layout [B*L, 512], bf16 ws (wave owns full k)
#pragma unroll
  for (int j = 0; j < 4; j++)
#pragma unroll
    for (int i = 0; i < 4; i++) {
      int rowg = q0 + qd * 4 + i;
      int col = h * 64 + j * 16 + n;
      ao[(size_t)(bb * 2048 + rowg) * 512 + col] = f2bf(oacc[j][i]);
    }
}

extern "C" void kernel_launch(void* const* d_in, const int* in_sizes, int n_in,
                              void* d_out, int out_size, void* d_ws, size_t ws_size,
                              hipStream_t stream) {
  (void)in_sizes; (void)n_in; (void)out_size; (void)ws_size;
  const float* q = (const float*)d_in[0];
  const float* k = (const float*)d_in[1];
  const float* v = (const float*)d_in[2];
  const int* mask = (const int*)d_in[3];

  float* out = (float*)d_out;
  float* attn = out + (size_t)4 * 2048 * 512;

  ushort* qp = (ushort*)d_ws;
  ushort* kp = qp + 4194304;
  ushort* vpT = kp + 4194304;
  ushort* ao = vpT + 4194304;

  // bf16 conversion scratch carved from the tail of the attn output buffer:
  // read only by proj1, overwritten later by attn_kernel. 480MB..505.5MB.
  char* attnB = (char*)attn;
  ushort* xq = (ushort*)(attnB + 503316480);
  ushort* xk = xq + 4194304;
  ushort* xv = xk + 4194304;
  ushort* wqb = xv + 4194304;
  ushort* wkb = wqb + 262144;
  ushort* wvb = wkb + 262144;

  CvtArgs6 cv;
  cv.a[0] = { q, xq, 1048576 };
  cv.a[1] = { k, xk, 1048576 };
  cv.a[2] = { v, xv, 1048576 };
  cv.a[3] = { (const float*)d_in[4], wqb, 65536 };
  cv.a[4] = { (const float*)d_in[6], wkb, 65536 };
  cv.a[5] = { (const float*)d_in[8], wvb, 65536 };
  convert_kernel<<<dim3(256, 6), 256, 0, stream>>>(cv);

  ProjArgs3 pa;
  pa.p[0] = { xq, wqb, (const float*)d_in[5], qp,  0.125f, 0, 0 };
  pa.p[1] = { xk, wkb, (const float*)d_in[7], kp,  1.0f,   0, 0 };
  pa.p[2] = { xv, wvb, (const float*)d_in[9], vpT, 1.0f,   1, 0 };
  proj_kernel<<<dim3(64, 8, 3), 256, 0, stream>>>(pa);

  attn_kernel<<<dim3(32, 8, 4), 256, 0, stream>>>(qp, kp, vpT, mask, attn, ao);

  ProjArgs3 po;
  po.p[0] = { ao, d_in[10], (const float*)d_in[11], out, 1.0f, 2, 1 };
  po.p[1] = po.p[0]; po.p[2] = po.p[0];
  proj_kernel<<<dim3(64, 8, 1), 256, 0, stream>>>(po);
}